// Round 2
// baseline (108.109 us; speedup 1.0000x reference)
//
#include <hip/hip_runtime.h>

#define TPB 256
// Per-thread private LDS slot: 16 float2 coords (A:0..7, B:8..15) + 1 pad.
// Stride 17 float2 = 136 B -> b64-aligned for every t; word-index stride
// 34 == 2 (mod 32) -> worst case 2-way bank aliasing, which is free (m136).
#define SLOT 17

// r17 (resubmit — r17 bench was an infra failure, theory untested).
// I$-thrash theory: r16 was ~35-40 KB of straight-line code (unrolled
// clip + clang-unrolled Jarvis) > 32 KB L1I; ~13 cyc/instr implied fetch
// stalls. This round: identical arithmetic in identical order, but the 16
// EDGE blocks become two 8-iteration loops over LDS-staged P-edges, and all
// loops are pinned with `#pragma unroll 1`. Target ~5 KB of code.
// Codegen law (r3..r15) otherwise preserved: serial chains, block-local
// temps, TPB=256, no register arrays, no in-loop shuffles.
__global__ __launch_bounds__(TPB, 2) void ciou_main(
    const float* __restrict__ A,
    const float* __restrict__ Bq,
    double* __restrict__ partial,
    int nbatch, int tail)
{
    const int t = threadIdx.x;
    const int i0 = blockIdx.x * TPB + t;
    const bool live = !tail || (i0 < nbatch);
    const int i = live ? i0 : (nbatch - 1);

    __shared__ float2 pts[TPB * SLOT];
    float2* myp = &pts[t * SLOT];

    float ax0,ax1,ax2,ax3,ax4,ax5,ax6,ax7;
    float ay0,ay1,ay2,ay3,ay4,ay5,ay6,ay7;
    float bx0,bx1,bx2,bx3,bx4,bx5,bx6,bx7;
    float by0,by1,by2,by3,by4,by5,by6,by7;
    {
        const float4* pa = (const float4*)(A + (size_t)i * 16);
        const float4* pb = (const float4*)(Bq + (size_t)i * 16);
        float4 q;
        q = pa[0]; ax0=q.x; ay0=q.y; ax1=q.z; ay1=q.w;
        myp[0] = make_float2(q.x,q.y); myp[1] = make_float2(q.z,q.w);
        q = pa[1]; ax2=q.x; ay2=q.y; ax3=q.z; ay3=q.w;
        myp[2] = make_float2(q.x,q.y); myp[3] = make_float2(q.z,q.w);
        q = pa[2]; ax4=q.x; ay4=q.y; ax5=q.z; ay5=q.w;
        myp[4] = make_float2(q.x,q.y); myp[5] = make_float2(q.z,q.w);
        q = pa[3]; ax6=q.x; ay6=q.y; ax7=q.z; ay7=q.w;
        myp[6] = make_float2(q.x,q.y); myp[7] = make_float2(q.z,q.w);
        q = pb[0]; bx0=q.x; by0=q.y; bx1=q.z; by1=q.w;
        myp[8] = make_float2(q.x,q.y); myp[9] = make_float2(q.z,q.w);
        q = pb[1]; bx2=q.x; by2=q.y; bx3=q.z; by3=q.w;
        myp[10] = make_float2(q.x,q.y); myp[11] = make_float2(q.z,q.w);
        q = pb[2]; bx4=q.x; by4=q.y; bx5=q.z; by5=q.w;
        myp[12] = make_float2(q.x,q.y); myp[13] = make_float2(q.z,q.w);
        q = pb[3]; bx6=q.x; by6=q.y; bx7=q.z; by7=q.w;
        myp[14] = make_float2(q.x,q.y); myp[15] = make_float2(q.z,q.w);
    }

    // Shoelace areas (input vertex order is CCW; sort_poly = rotation).
    float area_a = 0.5f * ((ax0*ay1-ay0*ax1) + (ax1*ay2-ay1*ax2)
                         + (ax2*ay3-ay2*ax3) + (ax3*ay4-ay3*ax4)
                         + (ax4*ay5-ay4*ax5) + (ax5*ay6-ay5*ax6)
                         + (ax6*ay7-ay6*ax7) + (ax7*ay0-ay7*ax0));
    float area_b = 0.5f * ((bx0*by1-by0*bx1) + (bx1*by2-by1*bx2)
                         + (bx2*by3-by2*bx3) + (bx3*by4-by3*bx4)
                         + (bx4*by5-by4*bx5) + (bx5*by6-by5*bx6)
                         + (bx6*by7-by6*bx7) + (bx7*by0-by7*bx0));

    // ---- Intersection: Green's theorem over clipped edges ----
    float inter2 = 0.f;

    // inside Q iff cross(E_Q, p - V_Q) >= 0; along edge: aa + t*bb >= 0.
    // Branchless: h = bb*1e38 (+big if bb>0, -big if bb<0); IEEE min/max
    // absorb the unused arm. bb==0 (parallel) is measure-zero (r10+ absmax 0).
#define HP(T0,T1,QX0,QY0,QX1,QY1) { \
        float ex = (QX1)-(QX0), ey = (QY1)-(QY0); \
        float aa = ex*(Py-(QY0)) - ey*(Px-(QX0)); \
        float bb = ex*Dy - ey*Dx; \
        float tc = __fdividef(-aa, bb); \
        float h = bb * 1e38f; \
        T0 = fmaxf(T0, fminf(tc, h)); \
        T1 = fminf(T1, fmaxf(tc, h)); }

#define HPB HP(t0a,t1a,bx0,by0,bx1,by1) HP(t0b,t1b,bx1,by1,bx2,by2) \
            HP(t0a,t1a,bx2,by2,bx3,by3) HP(t0b,t1b,bx3,by3,bx4,by4) \
            HP(t0a,t1a,bx4,by4,bx5,by5) HP(t0b,t1b,bx5,by5,bx6,by6) \
            HP(t0a,t1a,bx6,by6,bx7,by7) HP(t0b,t1b,bx7,by7,bx0,by0)
#define HPA HP(t0a,t1a,ax0,ay0,ax1,ay1) HP(t0b,t1b,ax1,ay1,ax2,ay2) \
            HP(t0a,t1a,ax2,ay2,ax3,ay3) HP(t0b,t1b,ax3,ay3,ax4,ay4) \
            HP(t0a,t1a,ax4,ay4,ax5,ay5) HP(t0b,t1b,ax5,ay5,ax6,ay6) \
            HP(t0a,t1a,ax6,ay6,ax7,ay7) HP(t0b,t1b,ax7,ay7,ax0,ay0)

    // A-edges clipped by B's half-planes. Same per-edge math and same
    // inter2 accumulation order (A0..A7) as r16 -> bit-identical.
#pragma unroll 1
    for (int e = 0; e < 8; ++e) {
        float2 P  = myp[e];
        float2 Pn = myp[(e + 1) & 7];
        const float Px = P.x, Py = P.y;
        const float Dx = Pn.x - Px, Dy = Pn.y - Py;
        float t0a = 0.f, t1a = 1.f, t0b = 0.f, t1b = 1.f;
        HPB
        float dt = fminf(t1a, t1b) - fmaxf(t0a, t0b);
        float cpd = Px*Dy - Py*Dx;
        inter2 += fmaxf(dt, 0.f) * cpd;
    }
    // B-edges clipped by A's half-planes (B0..B7).
#pragma unroll 1
    for (int e = 0; e < 8; ++e) {
        float2 P  = myp[8 + e];
        float2 Pn = myp[8 + ((e + 1) & 7)];
        const float Px = P.x, Py = P.y;
        const float Dx = Pn.x - Px, Dy = Pn.y - Py;
        float t0a = 0.f, t1a = 1.f, t0b = 0.f, t1b = 1.f;
        HPA
        float dt = fminf(t1a, t1b) - fmaxf(t0a, t0b);
        float cpd = Px*Dy - Py*Dx;
        inter2 += fmaxf(dt, 0.f) * cpd;
    }

    float inter = fmaxf(0.5f * inter2, 0.f);
    float uni = area_a + area_b - inter;
    float iou = __fdividef(inter, uni);

    // ---- Hull start: serial min by (y,x) over all 16 ----
    float stx = ax0, sty = ay0;
#define UPD(PX,PY) { \
        bool bs = ((PY) < sty) || (((PY) == sty) && ((PX) < stx)); \
        stx = bs ? (PX) : stx; sty = bs ? (PY) : sty; }
    UPD(ax1,ay1) UPD(ax2,ay2) UPD(ax3,ay3) UPD(ax4,ay4)
    UPD(ax5,ay5) UPD(ax6,ay6) UPD(ax7,ay7)
    UPD(bx0,by0) UPD(bx1,by1) UPD(bx2,by2) UPD(bx3,by3)
    UPD(bx4,by4) UPD(bx5,by5) UPD(bx6,by6) UPD(bx7,by7)

    // ---- Jarvis march, candidate seeded with negated incoming direction ----
    // (r9/r10-validated: every true candidate beats -din via cross<0; the
    // self-point gives cr==0, never taken; nx/ny select exact original
    // coords so the done-equality matches the reference's termination.)
    // r17: `#pragma unroll 1` — keep ONE copy of the 16-SCAN body in I$.
    float cxv = stx, cyv = sty, accH = 0.f;
    float pdx = 1.f, pdy = 0.f;          // reference's initial heading (1,0)
    bool done = false;
#pragma unroll 1
    for (int it = 0; it < 16; ++it) {
        float cdx = -pdx, cdy = -pdy;
        float nx = cxv, ny = cyv;
#define SCAN(PX,PY) { \
            float vx = (PX) - cxv, vy = (PY) - cyv; \
            float cr = cdx*vy - cdy*vx; \
            bool take = cr < 0.f; \
            nx = take ? (PX) : nx;  ny = take ? (PY) : ny; \
            cdx = take ? vx : cdx;  cdy = take ? vy : cdy; }
        SCAN(ax0,ay0) SCAN(ax1,ay1) SCAN(ax2,ay2) SCAN(ax3,ay3)
        SCAN(ax4,ay4) SCAN(ax5,ay5) SCAN(ax6,ay6) SCAN(ax7,ay7)
        SCAN(bx0,by0) SCAN(bx1,by1) SCAN(bx2,by2) SCAN(bx3,by3)
        SCAN(bx4,by4) SCAN(bx5,by5) SCAN(bx6,by6) SCAN(bx7,by7)
        accH += done ? 0.f : (cxv*ny - cyv*nx);
        done = done || (nx == stx && ny == sty);
        pdx = cdx; pdy = cdy;
        cxv = nx; cyv = ny;
        if (__all(done)) break;
    }
    float ch = 0.5f * accH;

    float val = iou - __fdividef(ch - uni, ch);
    float v = live ? val : 0.f;

    // ---- epilogue: shuffle -> LDS(16B) -> ONE plain store. Zero waits. ----
    #pragma unroll
    for (int off = 32; off > 0; off >>= 1) v += __shfl_down(v, off);
    __shared__ float wsum[4];
    int lane = t & 63, wid = t >> 6;
    if (lane == 0) wsum[wid] = v;
    __syncthreads();
    if (t == 0) {
        partial[blockIdx.x] = (double)wsum[0] + (double)wsum[1]
                            + (double)wsum[2] + (double)wsum[3];
    }
}

__global__ __launch_bounds__(256) void ciou_finalize(
    const double* __restrict__ partial, float* __restrict__ out,
    int nparts, int nbatch)
{
    double v = 0.0;
    for (int j = threadIdx.x; j < nparts; j += 256) v += partial[j];
    #pragma unroll
    for (int off = 32; off > 0; off >>= 1) v += __shfl_down(v, off);
    __shared__ double s[4];
    int lane = threadIdx.x & 63, wid = threadIdx.x >> 6;
    if (lane == 0) s[wid] = v;
    __syncthreads();
    if (threadIdx.x == 0)
        out[0] = (float)((s[0] + s[1] + s[2] + s[3]) / (double)nbatch);
}

extern "C" void kernel_launch(void* const* d_in, const int* in_sizes, int n_in,
                              void* d_out, int out_size, void* d_ws, size_t ws_size,
                              hipStream_t stream) {
    const float* a = (const float*)d_in[0];
    const float* b = (const float*)d_in[1];
    float* out = (float*)d_out;
    int nbatch = in_sizes[0] / 16;
    int nblocks = (nbatch + TPB - 1) / TPB;
    int tail = (nblocks * TPB != nbatch) ? 1 : 0;   // 262144: tail==0
    double* partial = (double*)d_ws;   // fully overwritten each call; no memset
    ciou_main<<<nblocks, TPB, 0, stream>>>(a, b, partial, nbatch, tail);
    ciou_finalize<<<1, 256, 0, stream>>>(partial, out, nblocks, nbatch);
}

// Round 3
// 101.443 us; speedup vs baseline: 1.0657x; 1.0657x over previous
//
#include <hip/hip_runtime.h>

#define TPB 256

// r18: ILP-restoration round. r2 profile: ciou_main 44.3us, VALUBusy 73%,
// HBM 4.9%, occupancy grid-capped at 4 waves/SIMD -> issue/latency-bound.
// r17's rolled clip loops killed r16's cross-EDGE ILP (neutral net).
//   - Clip: back to r16's fully-unrolled register EDGE blocks (bit-identical
//     math, proven codegen), no LDS staging. ~15 KB code, fits L1I.
//   - Jarvis: rolled (1 body in I$) but scan split into 4 independent
//     4-point chains + 3-merge tree: serial depth 112 -> ~35 per iter.
//     Wedge-angle total order => same winner, bit-identical (nx,ny,cd).
// Epilogue: unchanged r16 (shuffle -> 16B LDS -> one store + finalize).
__global__ __launch_bounds__(TPB, 2) void ciou_main(
    const float* __restrict__ A,
    const float* __restrict__ Bq,
    double* __restrict__ partial,
    int nbatch, int tail)
{
    const int t = threadIdx.x;
    const int i0 = blockIdx.x * TPB + t;
    const bool live = !tail || (i0 < nbatch);
    const int i = live ? i0 : (nbatch - 1);

    float ax0,ax1,ax2,ax3,ax4,ax5,ax6,ax7;
    float ay0,ay1,ay2,ay3,ay4,ay5,ay6,ay7;
    float bx0,bx1,bx2,bx3,bx4,bx5,bx6,bx7;
    float by0,by1,by2,by3,by4,by5,by6,by7;
    {
        const float4* pa = (const float4*)(A + (size_t)i * 16);
        const float4* pb = (const float4*)(Bq + (size_t)i * 16);
        float4 q;
        q = pa[0]; ax0=q.x; ay0=q.y; ax1=q.z; ay1=q.w;
        q = pa[1]; ax2=q.x; ay2=q.y; ax3=q.z; ay3=q.w;
        q = pa[2]; ax4=q.x; ay4=q.y; ax5=q.z; ay5=q.w;
        q = pa[3]; ax6=q.x; ay6=q.y; ax7=q.z; ay7=q.w;
        q = pb[0]; bx0=q.x; by0=q.y; bx1=q.z; by1=q.w;
        q = pb[1]; bx2=q.x; by2=q.y; bx3=q.z; by3=q.w;
        q = pb[2]; bx4=q.x; by4=q.y; bx5=q.z; by5=q.w;
        q = pb[3]; bx6=q.x; by6=q.y; bx7=q.z; by7=q.w;
    }

    // Shoelace areas (input vertex order is CCW; sort_poly = rotation).
    float area_a = 0.5f * ((ax0*ay1-ay0*ax1) + (ax1*ay2-ay1*ax2)
                         + (ax2*ay3-ay2*ax3) + (ax3*ay4-ay3*ax4)
                         + (ax4*ay5-ay4*ax5) + (ax5*ay6-ay5*ax6)
                         + (ax6*ay7-ay6*ax7) + (ax7*ay0-ay7*ax0));
    float area_b = 0.5f * ((bx0*by1-by0*bx1) + (bx1*by2-by1*bx2)
                         + (bx2*by3-by2*bx3) + (bx3*by4-by3*bx4)
                         + (bx4*by5-by4*bx5) + (bx5*by6-by5*bx6)
                         + (bx6*by7-by6*bx7) + (bx7*by0-by7*bx0));

    // ---- Intersection: Green's theorem over clipped edges ----
    float inter2 = 0.f;

    // inside Q iff cross(E_Q, p - V_Q) >= 0; along edge: aa + t*bb >= 0.
    // Branchless: h = bb*1e38 (+big if bb>0, -big if bb<0); IEEE min/max
    // absorb the unused arm. bb==0 (parallel) is measure-zero (r10+ absmax 0).
#define HP(T0,T1,QX0,QY0,QX1,QY1) { \
        float ex = (QX1)-(QX0), ey = (QY1)-(QY0); \
        float aa = ex*(Py-(QY0)) - ey*(Px-(QX0)); \
        float bb = ex*Dy - ey*Dx; \
        float tc = __fdividef(-aa, bb); \
        float h = bb * 1e38f; \
        T0 = fmaxf(T0, fminf(tc, h)); \
        T1 = fminf(T1, fmaxf(tc, h)); }

#define HPB HP(t0a,t1a,bx0,by0,bx1,by1) HP(t0b,t1b,bx1,by1,bx2,by2) \
            HP(t0a,t1a,bx2,by2,bx3,by3) HP(t0b,t1b,bx3,by3,bx4,by4) \
            HP(t0a,t1a,bx4,by4,bx5,by5) HP(t0b,t1b,bx5,by5,bx6,by6) \
            HP(t0a,t1a,bx6,by6,bx7,by7) HP(t0b,t1b,bx7,by7,bx0,by0)
#define HPA HP(t0a,t1a,ax0,ay0,ax1,ay1) HP(t0b,t1b,ax1,ay1,ax2,ay2) \
            HP(t0a,t1a,ax2,ay2,ax3,ay3) HP(t0b,t1b,ax3,ay3,ax4,ay4) \
            HP(t0a,t1a,ax4,ay4,ax5,ay5) HP(t0b,t1b,ax5,ay5,ax6,ay6) \
            HP(t0a,t1a,ax6,ay6,ax7,ay7) HP(t0b,t1b,ax7,ay7,ax0,ay0)

    // cross(P(t0),P(t1)) = (t1-t0)*cross(P,D); dt<=0 -> fmax gives exact 0.
#define EDGE(PX,PY,QX,QY,HPS) { \
        const float Px = (PX), Py = (PY); \
        const float Dx = (QX) - Px, Dy = (QY) - Py; \
        float t0a = 0.f, t1a = 1.f, t0b = 0.f, t1b = 1.f; \
        HPS \
        float dt = fminf(t1a, t1b) - fmaxf(t0a, t0b); \
        float cpd = Px*Dy - Py*Dx; \
        inter2 += fmaxf(dt, 0.f) * cpd; }

    EDGE(ax0,ay0,ax1,ay1,HPB) EDGE(ax1,ay1,ax2,ay2,HPB)
    EDGE(ax2,ay2,ax3,ay3,HPB) EDGE(ax3,ay3,ax4,ay4,HPB)
    EDGE(ax4,ay4,ax5,ay5,HPB) EDGE(ax5,ay5,ax6,ay6,HPB)
    EDGE(ax6,ay6,ax7,ay7,HPB) EDGE(ax7,ay7,ax0,ay0,HPB)
    EDGE(bx0,by0,bx1,by1,HPA) EDGE(bx1,by1,bx2,by2,HPA)
    EDGE(bx2,by2,bx3,by3,HPA) EDGE(bx3,by3,bx4,by4,HPA)
    EDGE(bx4,by4,bx5,by5,HPA) EDGE(bx5,by5,bx6,by6,HPA)
    EDGE(bx6,by6,bx7,by7,HPA) EDGE(bx7,by7,bx0,by0,HPA)

    float inter = fmaxf(0.5f * inter2, 0.f);
    float uni = area_a + area_b - inter;
    float iou = __fdividef(inter, uni);

    // ---- Hull start: serial min by (y,x) over all 16 ----
    float stx = ax0, sty = ay0;
#define UPD(PX,PY) { \
        bool bs = ((PY) < sty) || (((PY) == sty) && ((PX) < stx)); \
        stx = bs ? (PX) : stx; sty = bs ? (PY) : sty; }
    UPD(ax1,ay1) UPD(ax2,ay2) UPD(ax3,ay3) UPD(ax4,ay4)
    UPD(ax5,ay5) UPD(ax6,ay6) UPD(ax7,ay7)
    UPD(bx0,by0) UPD(bx1,by1) UPD(bx2,by2) UPD(bx3,by3)
    UPD(bx4,by4) UPD(bx5,by5) UPD(bx6,by6) UPD(bx7,by7)

    // ---- Jarvis march, 4-chain split tournament (r18) ----
    // Seed each chain with the negated incoming direction (r9/r10-validated:
    // every true candidate beats -pd via cross<0; self/prev points give
    // cr==0, never taken). At a hull vertex all candidates lie in a wedge
    // < pi => clockwise-angle order is a strict total order => the 4-chain
    // tournament selects the SAME point as the serial fold, with the same
    // bit-exact (nx,ny) and cd = P - c. Unbeaten-seed chains (cd == -pd)
    // lose every merge against a beaten chain and never win one.
#define SCANC(CDX,CDY,NX,NY,PX,PY) { \
        float vx = (PX) - cxv, vy = (PY) - cyv; \
        float cr = CDX*vy - CDY*vx; \
        bool take = cr < 0.f; \
        NX = take ? (PX) : NX;  NY = take ? (PY) : NY; \
        CDX = take ? vx : CDX;  CDY = take ? vy : CDY; }
#define MERGE(CDX,CDY,NX,NY,CDX2,CDY2,NX2,NY2) { \
        float cr = CDX*(CDY2) - CDY*(CDX2); \
        bool take = cr < 0.f; \
        NX = take ? (NX2) : NX;  NY = take ? (NY2) : NY; \
        CDX = take ? (CDX2) : CDX; CDY = take ? (CDY2) : CDY; }

    float cxv = stx, cyv = sty, accH = 0.f;
    float pdx = 1.f, pdy = 0.f;          // reference's initial heading (1,0)
    bool done = false;
#pragma unroll 1
    for (int it = 0; it < 16; ++it) {
        float cdx0 = -pdx, cdy0 = -pdy, nx0 = cxv, ny0 = cyv;
        float cdx1 = -pdx, cdy1 = -pdy, nx1 = cxv, ny1 = cyv;
        float cdx2 = -pdx, cdy2 = -pdy, nx2 = cxv, ny2 = cyv;
        float cdx3 = -pdx, cdy3 = -pdy, nx3 = cxv, ny3 = cyv;
        SCANC(cdx0,cdy0,nx0,ny0, ax0,ay0) SCANC(cdx0,cdy0,nx0,ny0, ax1,ay1)
        SCANC(cdx0,cdy0,nx0,ny0, ax2,ay2) SCANC(cdx0,cdy0,nx0,ny0, ax3,ay3)
        SCANC(cdx1,cdy1,nx1,ny1, ax4,ay4) SCANC(cdx1,cdy1,nx1,ny1, ax5,ay5)
        SCANC(cdx1,cdy1,nx1,ny1, ax6,ay6) SCANC(cdx1,cdy1,nx1,ny1, ax7,ay7)
        SCANC(cdx2,cdy2,nx2,ny2, bx0,by0) SCANC(cdx2,cdy2,nx2,ny2, bx1,by1)
        SCANC(cdx2,cdy2,nx2,ny2, bx2,by2) SCANC(cdx2,cdy2,nx2,ny2, bx3,by3)
        SCANC(cdx3,cdy3,nx3,ny3, bx4,by4) SCANC(cdx3,cdy3,nx3,ny3, bx5,by5)
        SCANC(cdx3,cdy3,nx3,ny3, bx6,by6) SCANC(cdx3,cdy3,nx3,ny3, bx7,by7)
        MERGE(cdx0,cdy0,nx0,ny0, cdx1,cdy1,nx1,ny1)
        MERGE(cdx2,cdy2,nx2,ny2, cdx3,cdy3,nx3,ny3)
        MERGE(cdx0,cdy0,nx0,ny0, cdx2,cdy2,nx2,ny2)
        accH += done ? 0.f : (cxv*ny0 - cyv*nx0);
        done = done || (nx0 == stx && ny0 == sty);
        pdx = cdx0; pdy = cdy0;
        cxv = nx0; cyv = ny0;
        if (__all(done)) break;
    }
    float ch = 0.5f * accH;

    float val = iou - __fdividef(ch - uni, ch);
    float v = live ? val : 0.f;

    // ---- epilogue: shuffle -> LDS(16B) -> ONE plain store. Zero waits. ----
    #pragma unroll
    for (int off = 32; off > 0; off >>= 1) v += __shfl_down(v, off);
    __shared__ float wsum[4];
    int lane = t & 63, wid = t >> 6;
    if (lane == 0) wsum[wid] = v;
    __syncthreads();
    if (t == 0) {
        partial[blockIdx.x] = (double)wsum[0] + (double)wsum[1]
                            + (double)wsum[2] + (double)wsum[3];
    }
}

__global__ __launch_bounds__(256) void ciou_finalize(
    const double* __restrict__ partial, float* __restrict__ out,
    int nparts, int nbatch)
{
    double v = 0.0;
    for (int j = threadIdx.x; j < nparts; j += 256) v += partial[j];
    #pragma unroll
    for (int off = 32; off > 0; off >>= 1) v += __shfl_down(v, off);
    __shared__ double s[4];
    int lane = threadIdx.x & 63, wid = threadIdx.x >> 6;
    if (lane == 0) s[wid] = v;
    __syncthreads();
    if (threadIdx.x == 0)
        out[0] = (float)((s[0] + s[1] + s[2] + s[3]) / (double)nbatch);
}

extern "C" void kernel_launch(void* const* d_in, const int* in_sizes, int n_in,
                              void* d_out, int out_size, void* d_ws, size_t ws_size,
                              hipStream_t stream) {
    const float* a = (const float*)d_in[0];
    const float* b = (const float*)d_in[1];
    float* out = (float*)d_out;
    int nbatch = in_sizes[0] / 16;
    int nblocks = (nbatch + TPB - 1) / TPB;
    int tail = (nblocks * TPB != nbatch) ? 1 : 0;   // 262144: tail==0
    double* partial = (double*)d_ws;   // fully overwritten each call; no memset
    ciou_main<<<nblocks, TPB, 0, stream>>>(a, b, partial, nbatch, tail);
    ciou_finalize<<<1, 256, 0, stream>>>(partial, out, nblocks, nbatch);
}